// Round 10
// baseline (7474.848 us; speedup 1.0000x reference)
//
#include <hip/hip_runtime.h>
#include <hip/hip_bf16.h>

// LSTM stack B=32, T=512, H=1024, L=2.  Round 8: R7 + cached staging + acquire fence.
//   R7 (3-hop barrier + chunked aux=17 staging) = 7.2us/step, PASSED.  The aux=17
//   bypass forces every wg to pull its h-panel from LLC (~900cy) every step.
//   R8 single change: staging DMA aux=0 (normal L1/L2 cached) + one agent-scope
//   ACQUIRE fence per step (s_waitcnt + buffer_inv sc1) right after the barrier,
//   before any h read.  ~16 wgs/XCD then share ONE L2 fill per 64KB panel
//   (~200-300cy post-fill vs ~900cy), cutting the L1 staging chain ~3x.
//   Coherence: producers drain h-stores to LLC BEFORE flag (proven R2-R7);
//   readers invalidate L2 AFTER barrier, BEFORE staging -> refill is fresh.
//   (R4/R5 never tested this: their 146KB static LDS >64KB limit blocked launch.)

typedef __attribute__((ext_vector_type(8))) short short8;
typedef __attribute__((ext_vector_type(4))) float f32x4;

__device__ __forceinline__ unsigned short f2bu(float f) {
    __hip_bfloat16 h = __float2bfloat16(f);
    return *(unsigned short*)&h;
}
__device__ __forceinline__ float b2f(unsigned short u) {
    __hip_bfloat16 h = *(__hip_bfloat16*)&u;
    return __bfloat162float(h);
}

// global -> LDS DMA, 16B/lane, PLAIN CACHED (aux=0).  Freshness guaranteed by the
// per-step acquire fence (buffer_inv) executed before these are issued.
// LDS dest = wave-uniform base + lane*16.
__device__ __forceinline__ void gl_lds16(const unsigned short* gp, unsigned short* lp) {
    __builtin_amdgcn_global_load_lds(
        (__attribute__((address_space(1))) void*)gp,
        (__attribute__((address_space(3))) void*)lp, 16, 0, 0);
}

__device__ __forceinline__ void ast8(unsigned short* p, unsigned long long v) {
    __hip_atomic_store((unsigned long long*)p, v, __ATOMIC_RELAXED, __HIP_MEMORY_SCOPE_AGENT);
}
__device__ __forceinline__ unsigned alf(const unsigned* p) {
    return __hip_atomic_load(p, __ATOMIC_RELAXED, __HIP_MEMORY_SCOPE_AGENT);
}
__device__ __forceinline__ f32x4 mfma16(short8 a, short8 b, f32x4 c) {
    return __builtin_amdgcn_mfma_f32_16x16x32_bf16(a, b, c, 0, 0, 0);
}

// ---------------------------------------------------------------- pack_x
__global__ __launch_bounds__(256) void pack_x(const float* __restrict__ x,
                                              unsigned short* __restrict__ xb) {
    int i = blockIdx.x * 256 + threadIdx.x;     // 4,194,304 float4 groups
    float4 v = ((const float4*)x)[i];
    ushort4 o;
    o.x = f2bu(v.x); o.y = f2bu(v.y); o.z = f2bu(v.z); o.w = f2bu(v.w);
    ((ushort4*)xb)[i] = o;
}

// ---------------------------------------------------------------- pack_w
// p = w*32 + gate*8 + c   <->  orig col = gate*1024 + w*8 + c
__global__ __launch_bounds__(256) void pack_w(const float* __restrict__ Wx,
                                              const float* __restrict__ Wh,
                                              unsigned short* __restrict__ Wxp,
                                              unsigned short* __restrict__ Whp0,
                                              unsigned short* __restrict__ Wcat) {
    __shared__ float tile[32][257];
    int mi = blockIdx.x >> 9;          // 0:Wx0 1:Wx1 2:Wh0 3:Wh1
    int rem = blockIdx.x & 511;
    int kb = rem >> 4;                 // 0..31  (32 k-rows each)
    int cb = rem & 15;                 // 0..15  (256 cols each)
    const float* src = (mi == 0) ? Wx : (mi == 1) ? (Wx + 4194304)
                     : (mi == 2) ? Wh : (Wh + 4194304);
    int tid = threadIdx.x;
    for (int pphase = 0; pphase < 8; ++pphase) {
        int row = pphase * 4 + (tid >> 6);
        int col4 = (tid & 63) * 4;
        float4 v = *(const float4*)(src + (size_t)(kb * 32 + row) * 4096 + cb * 256 + col4);
        tile[row][col4 + 0] = v.x; tile[row][col4 + 1] = v.y;
        tile[row][col4 + 2] = v.z; tile[row][col4 + 3] = v.w;
    }
    __syncthreads();
    int j = tid;
    int oc = cb * 256 + j;
    int gate = oc >> 10, hc = oc & 1023, w = hc >> 3, c = hc & 7;
    int p = w * 32 + gate * 8 + c;
    unsigned short* dst;
    if (mi == 0)      dst = Wxp  + (size_t)p * 1024 + kb * 32;
    else if (mi == 2) dst = Whp0 + (size_t)p * 1024 + kb * 32;
    else if (mi == 1) dst = Wcat + (size_t)p * 2048 + kb * 32;
    else              dst = Wcat + (size_t)p * 2048 + 1024 + kb * 32;
    for (int k = 0; k < 32; ++k) dst[k] = f2bu(tile[k][j]);
}

// ---------------------------------------------------------------- pack_misc
__global__ __launch_bounds__(256) void pack_misc(const float* __restrict__ b,
                                                 float* __restrict__ biasp,
                                                 unsigned* __restrict__ bars,
                                                 unsigned* __restrict__ hz) {
    int i = blockIdx.x * 256 + threadIdx.x;   // grid 256 -> 65536
    if (i < 4096) {
        int w = i >> 5, q = i & 31, gate = q >> 3, c = q & 7;
        biasp[i] = b[gate * 1024 + w * 8 + c];
    }
    if (i < 1024) bars[i] = 0u;
    hz[i] = 0u;   // 65536 uints = 256KB: both h0buf[2] and h1buf[2]
}

// ---------------------------------------------------------------- gemm_zx
// C[r][p] = sum_k A[r][k] * Bt[p][k] + biasp[p]; A rows r = b*512+t.
// Output packed: Zx[((p>>5)*512 + t)*32 + b][32] + (p&31)
__global__ __launch_bounds__(256) void gemm_zx(const unsigned short* __restrict__ A,
                                               const unsigned short* __restrict__ Bt,
                                               const float* __restrict__ biasp,
                                               unsigned short* __restrict__ Zx) {
    __shared__ unsigned short Ash[128 * 72];
    __shared__ unsigned short Bsh[128 * 72];
    int tid = threadIdx.x;
    int bn = blockIdx.x & 31, bm = blockIdx.x >> 5;
    int L = tid & 63, wv = tid >> 6;
    int wm = (wv >> 1) * 64, wn = (wv & 1) * 64;
    f32x4 acc[4][4];
    for (int mi = 0; mi < 4; ++mi)
        for (int ni = 0; ni < 4; ++ni)
            acc[mi][ni] = (f32x4){0.f, 0.f, 0.f, 0.f};
    const int rs = tid >> 3;
    const int ch = tid & 7;
    for (int kt = 0; kt < 16; ++kt) {
        int k0 = kt * 64;
        __syncthreads();
#pragma unroll
        for (int it = 0; it < 4; ++it) {
            int r = it * 32 + rs;
            short8 av = *(const short8*)(A + (size_t)(bm * 128 + r) * 1024 + k0 + ch * 8);
            short8 bv = *(const short8*)(Bt + (size_t)(bn * 128 + r) * 1024 + k0 + ch * 8);
            *(short8*)(Ash + r * 72 + ch * 8) = av;
            *(short8*)(Bsh + r * 72 + ch * 8) = bv;
        }
        __syncthreads();
#pragma unroll
        for (int ks = 0; ks < 2; ++ks) {
            int ko = ks * 32 + (L >> 4) * 8;
            short8 af[4], bfv[4];
#pragma unroll
            for (int i = 0; i < 4; ++i)
                af[i] = *(const short8*)(Ash + (wm + i * 16 + (L & 15)) * 72 + ko);
#pragma unroll
            for (int i = 0; i < 4; ++i)
                bfv[i] = *(const short8*)(Bsh + (wn + i * 16 + (L & 15)) * 72 + ko);
#pragma unroll
            for (int mi = 0; mi < 4; ++mi)
#pragma unroll
                for (int ni = 0; ni < 4; ++ni)
                    acc[mi][ni] = mfma16(af[mi], bfv[ni], acc[mi][ni]);
        }
    }
#pragma unroll
    for (int mi = 0; mi < 4; ++mi) {
        int gr0 = bm * 128 + wm + mi * 16 + (L >> 4) * 4;
#pragma unroll
        for (int i = 0; i < 4; ++i) {
            int gr = gr0 + i;
            int bnat = gr >> 9, t = gr & 511;
#pragma unroll
            for (int ni = 0; ni < 4; ++ni) {
                int p = bn * 128 + wn + ni * 16 + (L & 15);
                float v = acc[mi][ni][i] + biasp[p];
                size_t addr = (((size_t)(p >> 5) * 512 + t) * 32 + bnat) * 32 + (p & 31);
                Zx[addr] = f2bu(v);
            }
        }
    }
}

// ---------------------------------------------------------------- chunk staging
// One chunk = 32 rows x 64 elements (128B/row) = 4KB, staged by 4 gl_lds16 issues.
// LDS layout [32][64] row-major; in-row bytes XOR-swizzled by ((row&7)<<4) on the
// GLOBAL side (linear LDS dest, G21), undone on the ds_read side.
__device__ __forceinline__ void stage_chunk(const unsigned short* __restrict__ ap,
                                            int koff,
                                            unsigned short* __restrict__ buf,
                                            int L) {
    int r = L >> 3;                // 0..7
    int b = (L & 7) * 16;          // byte within 128B row-chunk
#pragma unroll
    for (int i = 0; i < 4; ++i) {
        int row = i * 8 + r;
        int e = (b ^ ((row & 7) << 4)) >> 1;
        gl_lds16(ap + (size_t)row * 1024 + koff + e, buf + i * 512);
    }
}

// ---------------------------------------------------------------- chunked MFMA
// 2-deep ping-pong pipeline: while MFMAs consume chunk c, chunk c+1 is in flight
// and chunk c+2 gets issued (into c's buffer, after lgkmcnt(0) retires c's reads).
// vmcnt(4) is junk-proof: chunk c has >=4 newer VMEM ops, retirement is in-order.
template<int LAY>
__device__ __forceinline__ void mfma_chunks(const unsigned short* __restrict__ ap,
                                            int kbase,
                                            unsigned short* __restrict__ b0,
                                            unsigned short* __restrict__ b1,
                                            const short8 (&bfr)[2][16],
                                            int L, int quad, int m_r,
                                            f32x4 (&acc)[2][2]) {
    constexpr int NC = LAY ? 8 : 4;
    stage_chunk(ap, kbase, b0, L);
    stage_chunk(ap, kbase + 64, b1, L);
    const int S = (m_r & 7) << 4;
    const int e0 = ((quad * 16) ^ S) >> 1;          // ksl=0 element offset
    const int e1 = ((64 + quad * 16) ^ S) >> 1;     // ksl=1 element offset
#pragma unroll
    for (int c = 0; c < NC; ++c) {
        unsigned short* bc = (c & 1) ? b1 : b0;
        if (c + 1 < NC) { asm volatile("s_waitcnt vmcnt(4)" ::: "memory"); }
        else            { asm volatile("s_waitcnt vmcnt(0)" ::: "memory"); }
        __builtin_amdgcn_sched_barrier(0);
        short8 a00 = *(const short8*)(bc + m_r * 64 + e0);
        short8 a10 = *(const short8*)(bc + (16 + m_r) * 64 + e0);
        short8 a01 = *(const short8*)(bc + m_r * 64 + e1);
        short8 a11 = *(const short8*)(bc + (16 + m_r) * 64 + e1);
        asm volatile("s_waitcnt lgkmcnt(0)" ::: "memory");
        __builtin_amdgcn_sched_barrier(0);
        if (c + 2 < NC) stage_chunk(ap, kbase + (c + 2) * 64, bc, L);
        acc[0][0] = mfma16(a00, bfr[0][2 * c], acc[0][0]);
        acc[0][1] = mfma16(a00, bfr[1][2 * c], acc[0][1]);
        acc[1][0] = mfma16(a10, bfr[0][2 * c], acc[1][0]);
        acc[1][1] = mfma16(a10, bfr[1][2 * c], acc[1][1]);
        acc[0][0] = mfma16(a01, bfr[0][2 * c + 1], acc[0][0]);
        acc[0][1] = mfma16(a01, bfr[1][2 * c + 1], acc[0][1]);
        acc[1][0] = mfma16(a11, bfr[0][2 * c + 1], acc[1][0]);
        acc[1][1] = mfma16(a11, bfr[1][2 * c + 1], acc[1][1]);
    }
}

// ---------------------------------------------------------------- lstm_fused
__global__ __launch_bounds__(256, 1) void lstm_fused(
        const unsigned short* __restrict__ Whp0,   // [4096][1024]
        const unsigned short* __restrict__ Wcat,   // [4096][2048]
        const unsigned short* __restrict__ Zx,     // [128][512][32][32]
        const float* __restrict__ bias,            // original b [2][4096]
        unsigned short* __restrict__ h0buf,        // [2][32][1024]
        unsigned short* __restrict__ h1buf,        // [2][32][1024]
        unsigned* __restrict__ flags,              // [256]; gen copies at +320+g*32
        float* __restrict__ out) {
    __shared__ unsigned short ash[4][2][2048];     // 32KB chunk dbuf (low LDS!)
    __shared__ float zs[4][32][32];                // 16KB
    __shared__ unsigned long long zx8[256];        // 2KB: 32x32 bf16 block
    __shared__ unsigned long long hl8[32];         // 256B: 32x8 bf16
    unsigned short* zxloc = (unsigned short*)zx8;
    unsigned short* hloc  = (unsigned short*)hl8;

    int tid = threadIdx.x, wgid = blockIdx.x;
    int lay = wgid >> 7, w = wgid & 127;
    int L = tid & 63, wv = tid >> 6;
    int m_r = L & 15, quad = L >> 4;
    int nk = lay ? 16 : 8;
    int K  = lay ? 2048 : 1024;
    unsigned short* b0 = &ash[wv][0][0];
    unsigned short* b1 = &ash[wv][1][0];

    // hoist B fragments from packed global weights (plain cached loads, once)
    short8 bfr[2][16];
    {
        const unsigned short* wb = lay ? (Wcat + (size_t)w * 32 * 2048)
                                       : (Whp0 + (size_t)w * 32 * 1024);
        for (int nt = 0; nt < 2; ++nt)
            for (int ks = 0; ks < nk; ++ks) {
                int n = nt * 16 + m_r;
                int k = wv * (K / 4) + ks * 32 + quad * 8;
                bfr[nt][ks] = *(const short8*)(wb + (size_t)n * K + k);
            }
    }
    // gate-thread mapping: tid -> (b, c)
    int gb = tid >> 3, gc = tid & 7;
    float bi0 = 0.f, bf0 = 0.f, bg0 = 0.f, bo0 = 0.f;
    if (lay) {
        bi0 = bias[4096 + 0 * 1024 + w * 8 + gc];
        bf0 = bias[4096 + 1 * 1024 + w * 8 + gc];
        bg0 = bias[4096 + 2 * 1024 + w * 8 + gc];
        bo0 = bias[4096 + 3 * 1024 + w * 8 + gc];
    }
    float creg = 0.f;

    for (int s = 0; s < 513; ++s) {
        int t = lay ? s - 1 : s;
        bool active = lay ? (s >= 1) : (s < 512);

        // Acquire: invalidate reader-side L1/L2 so cached staging below refills
        // from LLC (stale lines exist: same parity buffer was read 2 steps ago).
        __builtin_amdgcn_fence(__ATOMIC_ACQUIRE, "agent");

        // ---- Phase B: chunked stage + MFMA pipeline (data of step s-1 is
        //      guaranteed visible by the barrier at the end of iteration s-1)
        if (active) {
            const unsigned short* h0p = h0buf + ((s + 1) & 1) * 32768;
            const unsigned short* h1p = h1buf + ((s + 1) & 1) * 32768;
            const unsigned short* ap = (lay && wv >= 2) ? h1p : h0p;
            int kbase = lay ? ((wv >= 2) ? wv * 512 - 1024 : wv * 512) : wv * 256;
            if (!lay) {   // stage this step's Zx block (2KB contiguous) into LDS
                const unsigned long long* zb =
                    (const unsigned long long*)(Zx + ((size_t)w * 512 + t) * 1024);
                zx8[tid] = zb[tid];
            }
            f32x4 acc[2][2];
            for (int a = 0; a < 2; ++a)
                for (int bq = 0; bq < 2; ++bq)
                    acc[a][bq] = (f32x4){0.f, 0.f, 0.f, 0.f};
            if (lay) mfma_chunks<1>(ap, kbase, b0, b1, bfr, L, quad, m_r, acc);
            else     mfma_chunks<0>(ap, kbase, b0, b1, bfr, L, quad, m_r, acc);
#pragma unroll
            for (int mt = 0; mt < 2; ++mt)
#pragma unroll
                for (int nt = 0; nt < 2; ++nt)
#pragma unroll
                    for (int i = 0; i < 4; ++i)
                        zs[wv][mt * 16 + quad * 4 + i][nt * 16 + m_r] = acc[mt][nt][i];
        }
        __syncthreads();   // sync1: zs + zx8 ready

        // ---- Phase C: gate math
        float hval = 0.f, cnv = 0.f;
        if (active) {
            float zi = bi0, zf = bf0, zg = bg0, zo = bo0;
#pragma unroll
            for (int v = 0; v < 4; ++v) {
                zi += zs[v][gb][gc];      zf += zs[v][gb][8 + gc];
                zg += zs[v][gb][16 + gc]; zo += zs[v][gb][24 + gc];
            }
            if (!lay) {
                zi += b2f(zxloc[gb * 32 + gc]);      zf += b2f(zxloc[gb * 32 + 8 + gc]);
                zg += b2f(zxloc[gb * 32 + 16 + gc]); zo += b2f(zxloc[gb * 32 + 24 + gc]);
            }
            float si = 1.f / (1.f + __expf(-zi));
            float sf = 1.f / (1.f + __expf(-zf));
            float so = 1.f / (1.f + __expf(-zo));
            cnv = sf * creg + si * tanhf(zg);
            creg = cnv;
            hval = so * tanhf(cnv);
            hloc[gb * 8 + gc] = f2bu(hval);
        }
        __syncthreads();   // sync2: hloc ready

        // ---- Phase D: publish h to exchange buffer (wave0, LLC-direct)
        if (active && tid < 64) {
            int br = tid >> 1, half = tid & 1;
            unsigned long long v = *(unsigned long long*)(hloc + br * 8 + half * 4);
            unsigned short* dst = (lay ? h1buf : h0buf) + (s & 1) * 32768
                                  + br * 1024 + w * 8 + half * 4;
            ast8(dst, v);
        }
        // ---- 3-hop grid barrier (R2/R3 proven): flag -> wg0 aggregate -> 8 gen
        __syncthreads();   // drains each wave's vmcnt -> h stores are at LLC
        unsigned tgt = (unsigned)s + 1u;
        if (tid == 0)
            __hip_atomic_store(flags + wgid, tgt, __ATOMIC_RELAXED, __HIP_MEMORY_SCOPE_AGENT);
        if (wgid == 0 && tid < 64) {
            for (;;) {
                unsigned f0 = alf(flags + tid);
                unsigned f1 = alf(flags + 64 + tid);
                unsigned f2 = alf(flags + 128 + tid);
                unsigned f3 = alf(flags + 192 + tid);
                if (__all((f0 >= tgt) && (f1 >= tgt) && (f2 >= tgt) && (f3 >= tgt))) break;
                __builtin_amdgcn_s_sleep(2);
            }
            if (tid < 8)
                __hip_atomic_store(flags + 320 + tid * 32, tgt, __ATOMIC_RELAXED, __HIP_MEMORY_SCOPE_AGENT);
        }
        // out[] stores: off the critical path, overlap with the gen-line wait
        if (active) {
            if (lay) {
                out[((size_t)gb * 512 + t) * 1024 + w * 8 + gc] = hval;
                if (t == 511) {
                    out[16777216 + 32768 + gb * 1024 + w * 8 + gc] = hval;
                    out[16777216 + 65536 + 32768 + gb * 1024 + w * 8 + gc] = cnv;
                }
            } else if (t == 511) {
                out[16777216 + gb * 1024 + w * 8 + gc] = hval;
                out[16777216 + 65536 + gb * 1024 + w * 8 + gc] = cnv;
            }
        }
        if (tid == 0) {
            unsigned* g = flags + 320 + (wgid & 7) * 32;
            while (alf(g) < tgt)
                __builtin_amdgcn_s_sleep(2);
        }
        __syncthreads();
    }
}

// ---------------------------------------------------------------- launch
extern "C" void kernel_launch(void* const* d_in, const int* in_sizes, int n_in,
                              void* d_out, int out_size, void* d_ws, size_t ws_size,
                              hipStream_t stream) {
    const float* x  = (const float*)d_in[0];
    const float* Wx = (const float*)d_in[1];
    const float* Wh = (const float*)d_in[2];
    const float* bb = (const float*)d_in[3];

    char* ws = (char*)d_ws;
    unsigned short* Wxp  = (unsigned short*)ws;                       //  8MB [4096][1024]
    unsigned short* Whp0 = (unsigned short*)(ws + (8ull  << 20));     //  8MB [4096][1024]
    unsigned short* Wcat = (unsigned short*)(ws + (16ull << 20));     // 16MB [4096][2048]
    unsigned short* xb   = (unsigned short*)(ws + (32ull << 20));     // 32MB
    unsigned short* Zx   = (unsigned short*)(ws + (64ull << 20));     // 128MB
    char* misc           = ws + (192ull << 20);
    float* biasp         = (float*)misc;                              // 16KB
    unsigned* bars       = (unsigned*)(misc + (64 << 10));            // 4KB
    unsigned short* h0b  = (unsigned short*)(misc + (128 << 10));     // 128KB [2][32][1024]
    unsigned short* h1b  = (unsigned short*)(misc + (256 << 10));     // 128KB
    unsigned* hz         = (unsigned*)(misc + (128 << 10));           // both hbufs, 256KB

    float* out = (float*)d_out;

    pack_x<<<16384, 256, 0, stream>>>(x, xb);
    pack_w<<<2048, 256, 0, stream>>>(Wx, Wh, Wxp, Whp0, Wcat);
    pack_misc<<<256, 256, 0, stream>>>(bb, biasp, bars, hz);

    gemm_zx<<<4096, 256, 0, stream>>>(xb, Wxp, biasp, Zx);
    lstm_fused<<<256, 256, 0, stream>>>(Whp0, Wcat, Zx, bb, h0b, h1b, bars, out);
}

// Round 12
// 3969.229 us; speedup vs baseline: 1.8832x; 1.8832x over previous
//
#include <hip/hip_runtime.h>
#include <hip/hip_bf16.h>

// LSTM stack B=32, T=512, H=1024, L=2.  Round 10 (resubmit): R7 + 3-deep staging.
//   R8 (cached staging + per-step acquire fence) REGRESSED 2x (3690->7210us):
//   256 wgs' uncorrelated per-step buffer_inv wipe each other's L2 fills ->
//   every read becomes an LLC refill + invalidate overhead.  REVERTED to aux=17.
//   R10 single change vs R7: chunk pipeline 2-deep -> 3-deep (T >= lat/3 instead
//   of lat/2; saves ~1.2k cy on L1's 8-chunk chain).  LDS: 3 bufs x 4KB x 4 waves
//   = 48KB; zs (16KB) ALIASED onto each wave's buffer-0 (safe: zs written after
//   that wave's chunk reads retire in-order; read in Phase C after sync1; buf0
//   rewritten only after the global barrier).  Total static LDS 51456B (<64KB;
//   constraint from R4/R5: >64KB static LDS silently fails to launch).
//   vmcnt: wait 4*min(2,NC-1-c); chunk c's 4 DMAs are within the oldest 5
//   outstanding wherever the zx8 copy gets scheduled -> conservative-safe.

typedef __attribute__((ext_vector_type(8))) short short8;
typedef __attribute__((ext_vector_type(4))) float f32x4;

__device__ __forceinline__ unsigned short f2bu(float f) {
    __hip_bfloat16 h = __float2bfloat16(f);
    return *(unsigned short*)&h;
}
__device__ __forceinline__ float b2f(unsigned short u) {
    __hip_bfloat16 h = *(__hip_bfloat16*)&u;
    return __bfloat162float(h);
}

// global -> LDS DMA, 16B/lane, sc0|sc1 (LLC-coherent path, proven R2/R3/R6/R7).
// LDS dest = wave-uniform base + lane*16.
__device__ __forceinline__ void gl_lds16(const unsigned short* gp, unsigned short* lp) {
    __builtin_amdgcn_global_load_lds(
        (__attribute__((address_space(1))) void*)gp,
        (__attribute__((address_space(3))) void*)lp, 16, 0, 17);
}

__device__ __forceinline__ void ast8(unsigned short* p, unsigned long long v) {
    __hip_atomic_store((unsigned long long*)p, v, __ATOMIC_RELAXED, __HIP_MEMORY_SCOPE_AGENT);
}
__device__ __forceinline__ unsigned alf(const unsigned* p) {
    return __hip_atomic_load(p, __ATOMIC_RELAXED, __HIP_MEMORY_SCOPE_AGENT);
}
__device__ __forceinline__ f32x4 mfma16(short8 a, short8 b, f32x4 c) {
    return __builtin_amdgcn_mfma_f32_16x16x32_bf16(a, b, c, 0, 0, 0);
}

// ---------------------------------------------------------------- pack_x
__global__ __launch_bounds__(256) void pack_x(const float* __restrict__ x,
                                              unsigned short* __restrict__ xb) {
    int i = blockIdx.x * 256 + threadIdx.x;     // 4,194,304 float4 groups
    float4 v = ((const float4*)x)[i];
    ushort4 o;
    o.x = f2bu(v.x); o.y = f2bu(v.y); o.z = f2bu(v.z); o.w = f2bu(v.w);
    ((ushort4*)xb)[i] = o;
}

// ---------------------------------------------------------------- pack_w
// p = w*32 + gate*8 + c   <->  orig col = gate*1024 + w*8 + c
__global__ __launch_bounds__(256) void pack_w(const float* __restrict__ Wx,
                                              const float* __restrict__ Wh,
                                              unsigned short* __restrict__ Wxp,
                                              unsigned short* __restrict__ Whp0,
                                              unsigned short* __restrict__ Wcat) {
    __shared__ float tile[32][257];
    int mi = blockIdx.x >> 9;          // 0:Wx0 1:Wx1 2:Wh0 3:Wh1
    int rem = blockIdx.x & 511;
    int kb = rem >> 4;                 // 0..31  (32 k-rows each)
    int cb = rem & 15;                 // 0..15  (256 cols each)
    const float* src = (mi == 0) ? Wx : (mi == 1) ? (Wx + 4194304)
                     : (mi == 2) ? Wh : (Wh + 4194304);
    int tid = threadIdx.x;
    for (int pphase = 0; pphase < 8; ++pphase) {
        int row = pphase * 4 + (tid >> 6);
        int col4 = (tid & 63) * 4;
        float4 v = *(const float4*)(src + (size_t)(kb * 32 + row) * 4096 + cb * 256 + col4);
        tile[row][col4 + 0] = v.x; tile[row][col4 + 1] = v.y;
        tile[row][col4 + 2] = v.z; tile[row][col4 + 3] = v.w;
    }
    __syncthreads();
    int j = tid;
    int oc = cb * 256 + j;
    int gate = oc >> 10, hc = oc & 1023, w = hc >> 3, c = hc & 7;
    int p = w * 32 + gate * 8 + c;
    unsigned short* dst;
    if (mi == 0)      dst = Wxp  + (size_t)p * 1024 + kb * 32;
    else if (mi == 2) dst = Whp0 + (size_t)p * 1024 + kb * 32;
    else if (mi == 1) dst = Wcat + (size_t)p * 2048 + kb * 32;
    else              dst = Wcat + (size_t)p * 2048 + 1024 + kb * 32;
    for (int k = 0; k < 32; ++k) dst[k] = f2bu(tile[k][j]);
}

// ---------------------------------------------------------------- pack_misc
__global__ __launch_bounds__(256) void pack_misc(const float* __restrict__ b,
                                                 float* __restrict__ biasp,
                                                 unsigned* __restrict__ bars,
                                                 unsigned* __restrict__ hz) {
    int i = blockIdx.x * 256 + threadIdx.x;   // grid 256 -> 65536
    if (i < 4096) {
        int w = i >> 5, q = i & 31, gate = q >> 3, c = q & 7;
        biasp[i] = b[gate * 1024 + w * 8 + c];
    }
    if (i < 1024) bars[i] = 0u;
    hz[i] = 0u;   // 65536 uints = 256KB: both h0buf[2] and h1buf[2]
}

// ---------------------------------------------------------------- gemm_zx
// C[r][p] = sum_k A[r][k] * Bt[p][k] + biasp[p]; A rows r = b*512+t.
// Output packed: Zx[((p>>5)*512 + t)*32 + b][32] + (p&31)
__global__ __launch_bounds__(256) void gemm_zx(const unsigned short* __restrict__ A,
                                               const unsigned short* __restrict__ Bt,
                                               const float* __restrict__ biasp,
                                               unsigned short* __restrict__ Zx) {
    __shared__ unsigned short Ash[128 * 72];
    __shared__ unsigned short Bsh[128 * 72];
    int tid = threadIdx.x;
    int bn = blockIdx.x & 31, bm = blockIdx.x >> 5;
    int L = tid & 63, wv = tid >> 6;
    int wm = (wv >> 1) * 64, wn = (wv & 1) * 64;
    f32x4 acc[4][4];
    for (int mi = 0; mi < 4; ++mi)
        for (int ni = 0; ni < 4; ++ni)
            acc[mi][ni] = (f32x4){0.f, 0.f, 0.f, 0.f};
    const int rs = tid >> 3;
    const int ch = tid & 7;
    for (int kt = 0; kt < 16; ++kt) {
        int k0 = kt * 64;
        __syncthreads();
#pragma unroll
        for (int it = 0; it < 4; ++it) {
            int r = it * 32 + rs;
            short8 av = *(const short8*)(A + (size_t)(bm * 128 + r) * 1024 + k0 + ch * 8);
            short8 bv = *(const short8*)(Bt + (size_t)(bn * 128 + r) * 1024 + k0 + ch * 8);
            *(short8*)(Ash + r * 72 + ch * 8) = av;
            *(short8*)(Bsh + r * 72 + ch * 8) = bv;
        }
        __syncthreads();
#pragma unroll
        for (int ks = 0; ks < 2; ++ks) {
            int ko = ks * 32 + (L >> 4) * 8;
            short8 af[4], bfv[4];
#pragma unroll
            for (int i = 0; i < 4; ++i)
                af[i] = *(const short8*)(Ash + (wm + i * 16 + (L & 15)) * 72 + ko);
#pragma unroll
            for (int i = 0; i < 4; ++i)
                bfv[i] = *(const short8*)(Bsh + (wn + i * 16 + (L & 15)) * 72 + ko);
#pragma unroll
            for (int mi = 0; mi < 4; ++mi)
#pragma unroll
                for (int ni = 0; ni < 4; ++ni)
                    acc[mi][ni] = mfma16(af[mi], bfv[ni], acc[mi][ni]);
        }
    }
#pragma unroll
    for (int mi = 0; mi < 4; ++mi) {
        int gr0 = bm * 128 + wm + mi * 16 + (L >> 4) * 4;
#pragma unroll
        for (int i = 0; i < 4; ++i) {
            int gr = gr0 + i;
            int bnat = gr >> 9, t = gr & 511;
#pragma unroll
            for (int ni = 0; ni < 4; ++ni) {
                int p = bn * 128 + wn + ni * 16 + (L & 15);
                float v = acc[mi][ni][i] + biasp[p];
                size_t addr = (((size_t)(p >> 5) * 512 + t) * 32 + bnat) * 32 + (p & 31);
                Zx[addr] = f2bu(v);
            }
        }
    }
}

// ---------------------------------------------------------------- chunk staging
// One chunk = 32 rows x 64 elements (128B/row) = 4KB, staged by 4 gl_lds16 issues.
// LDS layout [32][64] row-major; in-row bytes XOR-swizzled by ((row&7)<<4) on the
// GLOBAL side (linear LDS dest, G21), undone on the ds_read side.
__device__ __forceinline__ void stage_chunk(const unsigned short* __restrict__ ap,
                                            int koff,
                                            unsigned short* __restrict__ buf,
                                            int L) {
    int r = L >> 3;                // 0..7
    int b = (L & 7) * 16;          // byte within 128B row-chunk
#pragma unroll
    for (int i = 0; i < 4; ++i) {
        int row = i * 8 + r;
        int e = (b ^ ((row & 7) << 4)) >> 1;
        gl_lds16(ap + (size_t)row * 1024 + koff + e, buf + i * 512);
    }
}

// ---------------------------------------------------------------- chunked MFMA
// 3-deep triple-buffer pipeline: chunks c, c+1, c+2 in flight; chunk c+3 issued
// into c's buffer after lgkmcnt(0) retires c's reads.  Wait vmcnt(4*min(2,rem)):
// chunk c's 4 DMAs are within the oldest 5 outstanding VMEM ops regardless of
// where the (L0-only) zx8 copy's load got scheduled -> conservative-safe.
template<int LAY>
__device__ __forceinline__ void mfma_chunks(const unsigned short* __restrict__ ap,
                                            int kbase,
                                            unsigned short* __restrict__ b0,
                                            unsigned short* __restrict__ b1,
                                            unsigned short* __restrict__ b2,
                                            const short8 (&bfr)[2][16],
                                            int L, int quad, int m_r,
                                            f32x4 (&acc)[2][2]) {
    constexpr int NC = LAY ? 8 : 4;
    stage_chunk(ap, kbase, b0, L);
    stage_chunk(ap, kbase + 64, b1, L);
    stage_chunk(ap, kbase + 128, b2, L);
    const int S = (m_r & 7) << 4;
    const int e0 = ((quad * 16) ^ S) >> 1;          // ksl=0 element offset
    const int e1 = ((64 + quad * 16) ^ S) >> 1;     // ksl=1 element offset
#pragma unroll
    for (int c = 0; c < NC; ++c) {
        unsigned short* bc = (c % 3 == 0) ? b0 : (c % 3 == 1) ? b1 : b2;
        if (NC - 1 - c >= 2)      { asm volatile("s_waitcnt vmcnt(8)" ::: "memory"); }
        else if (NC - 1 - c == 1) { asm volatile("s_waitcnt vmcnt(4)" ::: "memory"); }
        else                      { asm volatile("s_waitcnt vmcnt(0)" ::: "memory"); }
        __builtin_amdgcn_sched_barrier(0);
        short8 a00 = *(const short8*)(bc + m_r * 64 + e0);
        short8 a10 = *(const short8*)(bc + (16 + m_r) * 64 + e0);
        short8 a01 = *(const short8*)(bc + m_r * 64 + e1);
        short8 a11 = *(const short8*)(bc + (16 + m_r) * 64 + e1);
        asm volatile("s_waitcnt lgkmcnt(0)" ::: "memory");
        __builtin_amdgcn_sched_barrier(0);
        if (c + 3 < NC) stage_chunk(ap, kbase + (c + 3) * 64, bc, L);
        acc[0][0] = mfma16(a00, bfr[0][2 * c], acc[0][0]);
        acc[0][1] = mfma16(a00, bfr[1][2 * c], acc[0][1]);
        acc[1][0] = mfma16(a10, bfr[0][2 * c], acc[1][0]);
        acc[1][1] = mfma16(a10, bfr[1][2 * c], acc[1][1]);
        acc[0][0] = mfma16(a01, bfr[0][2 * c + 1], acc[0][0]);
        acc[0][1] = mfma16(a01, bfr[1][2 * c + 1], acc[0][1]);
        acc[1][0] = mfma16(a11, bfr[0][2 * c + 1], acc[1][0]);
        acc[1][1] = mfma16(a11, bfr[1][2 * c + 1], acc[1][1]);
    }
}

// ---------------------------------------------------------------- lstm_fused
__global__ __launch_bounds__(256, 1) void lstm_fused(
        const unsigned short* __restrict__ Whp0,   // [4096][1024]
        const unsigned short* __restrict__ Wcat,   // [4096][2048]
        const unsigned short* __restrict__ Zx,     // [128][512][32][32]
        const float* __restrict__ bias,            // original b [2][4096]
        unsigned short* __restrict__ h0buf,        // [2][32][1024]
        unsigned short* __restrict__ h1buf,        // [2][32][1024]
        unsigned* __restrict__ flags,              // [256]; gen copies at +320+g*32
        float* __restrict__ out) {
    // 48KB: per-wave 3x4KB chunk buffers.  zs[wv] (4KB of fp32 [32][32]) ALIASES
    // each wave's buffer 0: written only after that wave's last buf-0 read
    // retired (in-order dep through MFMA), read in Phase C after sync1, and
    // buf 0 is next overwritten only after the global barrier.
    __shared__ unsigned short ash[4][3][2048];
    __shared__ unsigned long long zx8[256];        // 2KB: 32x32 bf16 block
    __shared__ unsigned long long hl8[32];         // 256B: 32x8 bf16
    unsigned short* zxloc = (unsigned short*)zx8;
    unsigned short* hloc  = (unsigned short*)hl8;

    int tid = threadIdx.x, wgid = blockIdx.x;
    int lay = wgid >> 7, w = wgid & 127;
    int L = tid & 63, wv = tid >> 6;
    int m_r = L & 15, quad = L >> 4;
    int nk = lay ? 16 : 8;
    int K  = lay ? 2048 : 1024;
    unsigned short* b0 = &ash[wv][0][0];
    unsigned short* b1 = &ash[wv][1][0];
    unsigned short* b2 = &ash[wv][2][0];
    float* zsw = (float*)&ash[wv][0][0];           // this wave's zs [32][32]

    // hoist B fragments from packed global weights (plain cached loads, once)
    short8 bfr[2][16];
    {
        const unsigned short* wb = lay ? (Wcat + (size_t)w * 32 * 2048)
                                       : (Whp0 + (size_t)w * 32 * 1024);
        for (int nt = 0; nt < 2; ++nt)
            for (int ks = 0; ks < nk; ++ks) {
                int n = nt * 16 + m_r;
                int k = wv * (K / 4) + ks * 32 + quad * 8;
                bfr[nt][ks] = *(const short8*)(wb + (size_t)n * K + k);
            }
    }
    // gate-thread mapping: tid -> (b, c)
    int gb = tid >> 3, gc = tid & 7;
    float bi0 = 0.f, bf0 = 0.f, bg0 = 0.f, bo0 = 0.f;
    if (lay) {
        bi0 = bias[4096 + 0 * 1024 + w * 8 + gc];
        bf0 = bias[4096 + 1 * 1024 + w * 8 + gc];
        bg0 = bias[4096 + 2 * 1024 + w * 8 + gc];
        bo0 = bias[4096 + 3 * 1024 + w * 8 + gc];
    }
    float creg = 0.f;

    for (int s = 0; s < 513; ++s) {
        int t = lay ? s - 1 : s;
        bool active = lay ? (s >= 1) : (s < 512);

        // ---- Phase B: chunked stage + MFMA pipeline (data of step s-1 is
        //      guaranteed visible by the barrier at the end of iteration s-1)
        if (active) {
            const unsigned short* h0p = h0buf + ((s + 1) & 1) * 32768;
            const unsigned short* h1p = h1buf + ((s + 1) & 1) * 32768;
            const unsigned short* ap = (lay && wv >= 2) ? h1p : h0p;
            int kbase = lay ? ((wv >= 2) ? wv * 512 - 1024 : wv * 512) : wv * 256;
            if (!lay) {   // stage this step's Zx block (2KB contiguous) into LDS
                const unsigned long long* zb =
                    (const unsigned long long*)(Zx + ((size_t)w * 512 + t) * 1024);
                zx8[tid] = zb[tid];
            }
            f32x4 acc[2][2];
            for (int a = 0; a < 2; ++a)
                for (int bq = 0; bq < 2; ++bq)
                    acc[a][bq] = (f32x4){0.f, 0.f, 0.f, 0.f};
            if (lay) mfma_chunks<1>(ap, kbase, b0, b1, b2, bfr, L, quad, m_r, acc);
            else     mfma_chunks<0>(ap, kbase, b0, b1, b2, bfr, L, quad, m_r, acc);
            // zs write: aliases this wave's buf0 -- all buf0 reads retired above
#pragma unroll
            for (int mt = 0; mt < 2; ++mt)
#pragma unroll
                for (int nt = 0; nt < 2; ++nt)
#pragma unroll
                    for (int i = 0; i < 4; ++i)
                        zsw[(mt * 16 + quad * 4 + i) * 32 + nt * 16 + m_r] = acc[mt][nt][i];
        }
        __syncthreads();   // sync1: all waves' zs + zx8 ready

        // ---- Phase C: gate math
        float hval = 0.f, cnv = 0.f;
        if (active) {
            float zi = bi0, zf = bf0, zg = bg0, zo = bo0;
#pragma unroll
            for (int v = 0; v < 4; ++v) {
                const float* zv = (const float*)&ash[v][0][0];
                zi += zv[gb * 32 + gc];      zf += zv[gb * 32 + 8 + gc];
                zg += zv[gb * 32 + 16 + gc]; zo += zv[gb * 32 + 24 + gc];
            }
            if (!lay) {
                zi += b2f(zxloc[gb * 32 + gc]);      zf += b2f(zxloc[gb * 32 + 8 + gc]);
                zg += b2f(zxloc[gb * 32 + 16 + gc]); zo += b2f(zxloc[gb * 32 + 24 + gc]);
            }
            float si = 1.f / (1.f + __expf(-zi));
            float sf = 1.f / (1.f + __expf(-zf));
            float so = 1.f / (1.f + __expf(-zo));
            cnv = sf * creg + si * tanhf(zg);
            creg = cnv;
            hval = so * tanhf(cnv);
            hloc[gb * 8 + gc] = f2bu(hval);
        }
        __syncthreads();   // sync2: hloc ready

        // ---- Phase D: publish h to exchange buffer (wave0, LLC-direct)
        if (active && tid < 64) {
            int br = tid >> 1, half = tid & 1;
            unsigned long long v = *(unsigned long long*)(hloc + br * 8 + half * 4);
            unsigned short* dst = (lay ? h1buf : h0buf) + (s & 1) * 32768
                                  + br * 1024 + w * 8 + half * 4;
            ast8(dst, v);
        }
        // ---- 3-hop grid barrier (R2/R3/R7 proven): flag -> wg0 aggregate -> 8 gen
        __syncthreads();   // drains each wave's vmcnt -> h stores are at LLC
        unsigned tgt = (unsigned)s + 1u;
        if (tid == 0)
            __hip_atomic_store(flags + wgid, tgt, __ATOMIC_RELAXED, __HIP_MEMORY_SCOPE_AGENT);
        if (wgid == 0 && tid < 64) {
            for (;;) {
                unsigned f0 = alf(flags + tid);
                unsigned f1 = alf(flags + 64 + tid);
                unsigned f2 = alf(flags + 128 + tid);
                unsigned f3 = alf(flags + 192 + tid);
                if (__all((f0 >= tgt) && (f1 >= tgt) && (f2 >= tgt) && (f3 >= tgt))) break;
                __builtin_amdgcn_s_sleep(2);
            }
            if (tid < 8)
                __hip_atomic_store(flags + 320 + tid * 32, tgt, __ATOMIC_RELAXED, __HIP_MEMORY_SCOPE_AGENT);
        }
        // out[] stores: off the critical path, overlap with the gen-line wait
        if (active) {
            if (lay) {
                out[((size_t)gb * 512 + t) * 1024 + w * 8 + gc] = hval;
                if (t == 511) {
                    out[16777216 + 32768 + gb * 1024 + w * 8 + gc] = hval;
                    out[16777216 + 65536 + 32768 + gb * 1024 + w * 8 + gc] = cnv;
                }
            } else if (t == 511) {
                out[16777216 + gb * 1024 + w * 8 + gc] = hval;
                out[16777216 + 65536 + gb * 1024 + w * 8 + gc] = cnv;
            }
        }
        if (tid == 0) {
            unsigned* g = flags + 320 + (wgid & 7) * 32;
            while (alf(g) < tgt)
                __builtin_amdgcn_s_sleep(2);
        }
        __syncthreads();
    }
}

// ---------------------------------------------------------------- launch
extern "C" void kernel_launch(void* const* d_in, const int* in_sizes, int n_in,
                              void* d_out, int out_size, void* d_ws, size_t ws_size,
                              hipStream_t stream) {
    const float* x  = (const float*)d_in[0];
    const float* Wx = (const float*)d_in[1];
    const float* Wh = (const float*)d_in[2];
    const float* bb = (const float*)d_in[3];

    char* ws = (char*)d_ws;
    unsigned short* Wxp  = (unsigned short*)ws;                       //  8MB [4096][1024]
    unsigned short* Whp0 = (unsigned short*)(ws + (8ull  << 20));     //  8MB [4096][1024]
    unsigned short* Wcat = (unsigned short*)(ws + (16ull << 20));     // 16MB [4096][2048]
    unsigned short* xb   = (unsigned short*)(ws + (32ull << 20));     // 32MB
    unsigned short* Zx   = (unsigned short*)(ws + (64ull << 20));     // 128MB
    char* misc           = ws + (192ull << 20);
    float* biasp         = (float*)misc;                              // 16KB
    unsigned* bars       = (unsigned*)(misc + (64 << 10));            // 4KB
    unsigned short* h0b  = (unsigned short*)(misc + (128 << 10));     // 128KB [2][32][1024]
    unsigned short* h1b  = (unsigned short*)(misc + (256 << 10));     // 128KB
    unsigned* hz         = (unsigned*)(misc + (128 << 10));           // both hbufs, 256KB

    float* out = (float*)d_out;

    pack_x<<<16384, 256, 0, stream>>>(x, xb);
    pack_w<<<2048, 256, 0, stream>>>(Wx, Wh, Wxp, Whp0, Wcat);
    pack_misc<<<256, 256, 0, stream>>>(bb, biasp, bars, hz);

    gemm_zx<<<4096, 256, 0, stream>>>(xb, Wxp, biasp, Zx);
    lstm_fused<<<256, 256, 0, stream>>>(Whp0, Wcat, Zx, bb, h0b, h1b, bars, out);
}

// Round 13
// 3885.357 us; speedup vs baseline: 1.9239x; 1.0216x over previous
//
#include <hip/hip_runtime.h>
#include <hip/hip_bf16.h>

// LSTM stack B=32, T=512, H=1024, L=2.  Round 13: split per-layer epoch barrier.
//   R10 (3-deep staging) = null vs R7 (7.2us/step both) -> step is BARRIER-bound,
//   not staging-bound.  R13 restructures sync:
//   - h0buf/h1buf deepened to 4 slots (write slot s&3, read slot (s-1)&3).
//     WAR distance becomes 3 steps -> L0 only tightly needs its OWN layer flags.
//   - Flags: l0flags[0..127], l1flags[128..255].  wg0 aggregates {l0>=t, l1>=t-2}
//     -> posts genA (polled by L0) and genB (polled by L1 phase-1).  wg128
//     aggregates {l0>=t, l1>=t} -> posts genC (polled by L1 phase-2).
//   - L1 K-split: ALL 4 waves cover y0 (k 0..1023, 4 chunks) after the EARLY
//     genB wait, then all 4 cover h1 (k 1024..2047, 4 chunks) after genC.
//     Post-recurrence-signal work halves (8 -> 4 staged chunks).
//   Steady state: period ~ L1 {3 gen hops + 4-chunk stage + gates + publish},
//   L0 decoupled in its 2-step slack; 256-wide straggler coupling removed.

typedef __attribute__((ext_vector_type(8))) short short8;
typedef __attribute__((ext_vector_type(4))) float f32x4;

__device__ __forceinline__ unsigned short f2bu(float f) {
    __hip_bfloat16 h = __float2bfloat16(f);
    return *(unsigned short*)&h;
}
__device__ __forceinline__ float b2f(unsigned short u) {
    __hip_bfloat16 h = *(__hip_bfloat16*)&u;
    return __bfloat162float(h);
}

// global -> LDS DMA, 16B/lane, sc0|sc1 (LLC-coherent path, proven R2/R3/R6/R7).
__device__ __forceinline__ void gl_lds16(const unsigned short* gp, unsigned short* lp) {
    __builtin_amdgcn_global_load_lds(
        (__attribute__((address_space(1))) void*)gp,
        (__attribute__((address_space(3))) void*)lp, 16, 0, 17);
}

__device__ __forceinline__ void ast8(unsigned short* p, unsigned long long v) {
    __hip_atomic_store((unsigned long long*)p, v, __ATOMIC_RELAXED, __HIP_MEMORY_SCOPE_AGENT);
}
__device__ __forceinline__ void astf(unsigned* p, unsigned v) {
    __hip_atomic_store(p, v, __ATOMIC_RELAXED, __HIP_MEMORY_SCOPE_AGENT);
}
__device__ __forceinline__ unsigned alf(const unsigned* p) {
    return __hip_atomic_load(p, __ATOMIC_RELAXED, __HIP_MEMORY_SCOPE_AGENT);
}
__device__ __forceinline__ f32x4 mfma16(short8 a, short8 b, f32x4 c) {
    return __builtin_amdgcn_mfma_f32_16x16x32_bf16(a, b, c, 0, 0, 0);
}

// ---------------------------------------------------------------- pack_x
__global__ __launch_bounds__(256) void pack_x(const float* __restrict__ x,
                                              unsigned short* __restrict__ xb) {
    int i = blockIdx.x * 256 + threadIdx.x;     // 4,194,304 float4 groups
    float4 v = ((const float4*)x)[i];
    ushort4 o;
    o.x = f2bu(v.x); o.y = f2bu(v.y); o.z = f2bu(v.z); o.w = f2bu(v.w);
    ((ushort4*)xb)[i] = o;
}

// ---------------------------------------------------------------- pack_w
// p = w*32 + gate*8 + c   <->  orig col = gate*1024 + w*8 + c
__global__ __launch_bounds__(256) void pack_w(const float* __restrict__ Wx,
                                              const float* __restrict__ Wh,
                                              unsigned short* __restrict__ Wxp,
                                              unsigned short* __restrict__ Whp0,
                                              unsigned short* __restrict__ Wcat) {
    __shared__ float tile[32][257];
    int mi = blockIdx.x >> 9;          // 0:Wx0 1:Wx1 2:Wh0 3:Wh1
    int rem = blockIdx.x & 511;
    int kb = rem >> 4;                 // 0..31  (32 k-rows each)
    int cb = rem & 15;                 // 0..15  (256 cols each)
    const float* src = (mi == 0) ? Wx : (mi == 1) ? (Wx + 4194304)
                     : (mi == 2) ? Wh : (Wh + 4194304);
    int tid = threadIdx.x;
    for (int pphase = 0; pphase < 8; ++pphase) {
        int row = pphase * 4 + (tid >> 6);
        int col4 = (tid & 63) * 4;
        float4 v = *(const float4*)(src + (size_t)(kb * 32 + row) * 4096 + cb * 256 + col4);
        tile[row][col4 + 0] = v.x; tile[row][col4 + 1] = v.y;
        tile[row][col4 + 2] = v.z; tile[row][col4 + 3] = v.w;
    }
    __syncthreads();
    int j = tid;
    int oc = cb * 256 + j;
    int gate = oc >> 10, hc = oc & 1023, w = hc >> 3, c = hc & 7;
    int p = w * 32 + gate * 8 + c;
    unsigned short* dst;
    if (mi == 0)      dst = Wxp  + (size_t)p * 1024 + kb * 32;
    else if (mi == 2) dst = Whp0 + (size_t)p * 1024 + kb * 32;
    else if (mi == 1) dst = Wcat + (size_t)p * 2048 + kb * 32;
    else              dst = Wcat + (size_t)p * 2048 + 1024 + kb * 32;
    for (int k = 0; k < 32; ++k) dst[k] = f2bu(tile[k][j]);
}

// ---------------------------------------------------------------- pack_misc
__global__ __launch_bounds__(256) void pack_misc(const float* __restrict__ b,
                                                 float* __restrict__ biasp,
                                                 unsigned* __restrict__ bars,
                                                 unsigned* __restrict__ hz) {
    int i = blockIdx.x * 256 + threadIdx.x;   // grid 256 -> 65536
    if (i < 4096) {
        int w = i >> 5, q = i & 31, gate = q >> 3, c = q & 7;
        biasp[i] = b[gate * 1024 + w * 8 + c];
    }
    if (i < 2048) bars[i] = 0u;               // flags + all gen lines
    hz[i] = 0u;                                // 512KB: h0buf[4] + h1buf[4]
    hz[i + 65536] = 0u;
}

// ---------------------------------------------------------------- gemm_zx
// C[r][p] = sum_k A[r][k] * Bt[p][k] + biasp[p]; A rows r = b*512+t.
// Output packed: Zx[((p>>5)*512 + t)*32 + b][32] + (p&31)
__global__ __launch_bounds__(256) void gemm_zx(const unsigned short* __restrict__ A,
                                               const unsigned short* __restrict__ Bt,
                                               const float* __restrict__ biasp,
                                               unsigned short* __restrict__ Zx) {
    __shared__ unsigned short Ash[128 * 72];
    __shared__ unsigned short Bsh[128 * 72];
    int tid = threadIdx.x;
    int bn = blockIdx.x & 31, bm = blockIdx.x >> 5;
    int L = tid & 63, wv = tid >> 6;
    int wm = (wv >> 1) * 64, wn = (wv & 1) * 64;
    f32x4 acc[4][4];
    for (int mi = 0; mi < 4; ++mi)
        for (int ni = 0; ni < 4; ++ni)
            acc[mi][ni] = (f32x4){0.f, 0.f, 0.f, 0.f};
    const int rs = tid >> 3;
    const int ch = tid & 7;
    for (int kt = 0; kt < 16; ++kt) {
        int k0 = kt * 64;
        __syncthreads();
#pragma unroll
        for (int it = 0; it < 4; ++it) {
            int r = it * 32 + rs;
            short8 av = *(const short8*)(A + (size_t)(bm * 128 + r) * 1024 + k0 + ch * 8);
            short8 bv = *(const short8*)(Bt + (size_t)(bn * 128 + r) * 1024 + k0 + ch * 8);
            *(short8*)(Ash + r * 72 + ch * 8) = av;
            *(short8*)(Bsh + r * 72 + ch * 8) = bv;
        }
        __syncthreads();
#pragma unroll
        for (int ks = 0; ks < 2; ++ks) {
            int ko = ks * 32 + (L >> 4) * 8;
            short8 af[4], bfv[4];
#pragma unroll
            for (int i = 0; i < 4; ++i)
                af[i] = *(const short8*)(Ash + (wm + i * 16 + (L & 15)) * 72 + ko);
#pragma unroll
            for (int i = 0; i < 4; ++i)
                bfv[i] = *(const short8*)(Bsh + (wn + i * 16 + (L & 15)) * 72 + ko);
#pragma unroll
            for (int mi = 0; mi < 4; ++mi)
#pragma unroll
                for (int ni = 0; ni < 4; ++ni)
                    acc[mi][ni] = mfma16(af[mi], bfv[ni], acc[mi][ni]);
        }
    }
#pragma unroll
    for (int mi = 0; mi < 4; ++mi) {
        int gr0 = bm * 128 + wm + mi * 16 + (L >> 4) * 4;
#pragma unroll
        for (int i = 0; i < 4; ++i) {
            int gr = gr0 + i;
            int bnat = gr >> 9, t = gr & 511;
#pragma unroll
            for (int ni = 0; ni < 4; ++ni) {
                int p = bn * 128 + wn + ni * 16 + (L & 15);
                float v = acc[mi][ni][i] + biasp[p];
                size_t addr = (((size_t)(p >> 5) * 512 + t) * 32 + bnat) * 32 + (p & 31);
                Zx[addr] = f2bu(v);
            }
        }
    }
}

// ---------------------------------------------------------------- chunk staging
// One chunk = 32 rows x 64 elements (128B/row) = 4KB, staged by 4 gl_lds16 issues.
// In-row bytes XOR-swizzled by ((row&7)<<4) on the GLOBAL side (linear LDS dest,
// G21), undone on the ds_read side.
__device__ __forceinline__ void stage_chunk(const unsigned short* __restrict__ ap,
                                            int koff,
                                            unsigned short* __restrict__ buf,
                                            int L) {
    int r = L >> 3;                // 0..7
    int b = (L & 7) * 16;          // byte within 128B row-chunk
#pragma unroll
    for (int i = 0; i < 4; ++i) {
        int row = i * 8 + r;
        int e = (b ^ ((row & 7) << 4)) >> 1;
        gl_lds16(ap + (size_t)row * 1024 + koff + e, buf + i * 512);
    }
}

// ---------------------------------------------------------------- chunked MFMA
// 4 chunks, 3-deep triple-buffer (proven R10).  bofs selects bfr slots (0 or 8).
// vmcnt ladder 8/8/4/0: chunk c's 4 DMAs are within the oldest 5 outstanding
// wherever the (L0-only) zx8 load got scheduled -> conservative-safe.
__device__ __forceinline__ void mfma_chunks4(const unsigned short* __restrict__ ap,
                                             int kbase, int bofs,
                                             unsigned short* __restrict__ b0,
                                             unsigned short* __restrict__ b1,
                                             unsigned short* __restrict__ b2,
                                             const short8 (&bfr)[2][16],
                                             int L, int quad, int m_r,
                                             f32x4 (&acc)[2][2]) {
    stage_chunk(ap, kbase, b0, L);
    stage_chunk(ap, kbase + 64, b1, L);
    stage_chunk(ap, kbase + 128, b2, L);
    const int S = (m_r & 7) << 4;
    const int e0 = ((quad * 16) ^ S) >> 1;
    const int e1 = ((64 + quad * 16) ^ S) >> 1;
#pragma unroll
    for (int c = 0; c < 4; ++c) {
        unsigned short* bc = (c == 0 || c == 3) ? b0 : (c == 1) ? b1 : b2;
        if (c <= 1)      { asm volatile("s_waitcnt vmcnt(8)" ::: "memory"); }
        else if (c == 2) { asm volatile("s_waitcnt vmcnt(4)" ::: "memory"); }
        else             { asm volatile("s_waitcnt vmcnt(0)" ::: "memory"); }
        __builtin_amdgcn_sched_barrier(0);
        short8 a00 = *(const short8*)(bc + m_r * 64 + e0);
        short8 a10 = *(const short8*)(bc + (16 + m_r) * 64 + e0);
        short8 a01 = *(const short8*)(bc + m_r * 64 + e1);
        short8 a11 = *(const short8*)(bc + (16 + m_r) * 64 + e1);
        asm volatile("s_waitcnt lgkmcnt(0)" ::: "memory");
        __builtin_amdgcn_sched_barrier(0);
        if (c == 0) stage_chunk(ap, kbase + 192, bc, L);
        acc[0][0] = mfma16(a00, bfr[0][bofs + 2 * c], acc[0][0]);
        acc[0][1] = mfma16(a00, bfr[1][bofs + 2 * c], acc[0][1]);
        acc[1][0] = mfma16(a10, bfr[0][bofs + 2 * c], acc[1][0]);
        acc[1][1] = mfma16(a10, bfr[1][bofs + 2 * c], acc[1][1]);
        acc[0][0] = mfma16(a01, bfr[0][bofs + 2 * c + 1], acc[0][0]);
        acc[0][1] = mfma16(a01, bfr[1][bofs + 2 * c + 1], acc[0][1]);
        acc[1][0] = mfma16(a11, bfr[0][bofs + 2 * c + 1], acc[1][0]);
        acc[1][1] = mfma16(a11, bfr[1][bofs + 2 * c + 1], acc[1][1]);
    }
}

// ---------------------------------------------------------------- lstm_fused
__global__ __launch_bounds__(256, 1) void lstm_fused(
        const unsigned short* __restrict__ Whp0,   // [4096][1024]
        const unsigned short* __restrict__ Wcat,   // [4096][2048]
        const unsigned short* __restrict__ Zx,     // [128][512][32][32]
        const float* __restrict__ bias,            // original b [2][4096]
        unsigned short* __restrict__ h0buf,        // [4][32][1024] slots
        unsigned short* __restrict__ h1buf,        // [4][32][1024] slots
        unsigned* __restrict__ flags,              // [2048] region, see layout
        float* __restrict__ out) {
    // flags layout: [0..255] per-wg step flags; genA @320+g*32 (L0 poll);
    //               genB @576+g*32 (L1 y0 poll); genC @832+g*32 (L1 h1 poll).
    __shared__ unsigned short ash[4][3][2048];     // 48KB; zs aliases buf0 (R10)
    __shared__ unsigned long long zx8[256];        // 2KB
    __shared__ unsigned long long hl8[32];         // 256B
    unsigned short* zxloc = (unsigned short*)zx8;
    unsigned short* hloc  = (unsigned short*)hl8;

    int tid = threadIdx.x, wgid = blockIdx.x;
    int lay = wgid >> 7, w = wgid & 127;
    int L = tid & 63, wv = tid >> 6;
    int m_r = L & 15, quad = L >> 4;
    int nk = lay ? 16 : 8;
    int K  = lay ? 2048 : 1024;
    unsigned short* b0 = &ash[wv][0][0];
    unsigned short* b1 = &ash[wv][1][0];
    unsigned short* b2 = &ash[wv][2][0];
    float* zsw = (float*)&ash[wv][0][0];

    // hoist B fragments.  L0: k = wv*256 + ks*32 (+quad*8).
    // L1 NEW split: ks 0..7 -> y0 k = wv*256 + ks*32; ks 8..15 -> h1 k = 1024 + wv*256 + (ks-8)*32.
    short8 bfr[2][16];
    {
        const unsigned short* wb = lay ? (Wcat + (size_t)w * 32 * 2048)
                                       : (Whp0 + (size_t)w * 32 * 1024);
        for (int nt = 0; nt < 2; ++nt)
            for (int ks = 0; ks < nk; ++ks) {
                int n = nt * 16 + m_r;
                int k;
                if (!lay)        k = wv * 256 + ks * 32 + quad * 8;
                else if (ks < 8) k = wv * 256 + ks * 32 + quad * 8;
                else             k = 1024 + wv * 256 + (ks - 8) * 32 + quad * 8;
                bfr[nt][ks] = *(const short8*)(wb + (size_t)n * K + k);
            }
    }
    int gb = tid >> 3, gc = tid & 7;
    float bi0 = 0.f, bf0 = 0.f, bg0 = 0.f, bo0 = 0.f;
    if (lay) {
        bi0 = bias[4096 + 0 * 1024 + w * 8 + gc];
        bf0 = bias[4096 + 1 * 1024 + w * 8 + gc];
        bg0 = bias[4096 + 2 * 1024 + w * 8 + gc];
        bo0 = bias[4096 + 3 * 1024 + w * 8 + gc];
    }
    float creg = 0.f;
    const unsigned* genA = flags + 320 + (wgid & 7) * 32;
    const unsigned* genB = flags + 576 + (wgid & 7) * 32;
    const unsigned* genC = flags + 832 + (wgid & 7) * 32;

    for (int s = 0; s < 513; ++s) {
        int t = lay ? s - 1 : s;
        bool active = lay ? (s >= 1) : (s < 512);
        int rdslot = ((s + 3) & 3) * 32768;   // slot (s-1)&3
        int wrslot = (s & 3) * 32768;

        f32x4 acc[2][2];
        for (int a = 0; a < 2; ++a)
            for (int bq = 0; bq < 2; ++bq)
                acc[a][bq] = (f32x4){0.f, 0.f, 0.f, 0.f};

        if (!lay) {
            // ---- L0: wait genA >= s (own-layer RAW + 2-step-slack WAR)
            if (tid == 0)
                while (alf(genA) < (unsigned)s) __builtin_amdgcn_s_sleep(2);
            __syncthreads();
            if (active) {
                if (true) {   // stage Zx block
                    const unsigned long long* zb =
                        (const unsigned long long*)(Zx + ((size_t)w * 512 + t) * 1024);
                    zx8[tid] = zb[tid];
                }
                mfma_chunks4(h0buf + rdslot, wv * 256, 0, b0, b1, b2,
                             bfr, L, quad, m_r, acc);
            }
        } else {
            // ---- L1 phase 1: wait genB >= s (y0 ready), compute y0 half
            if (tid == 0)
                while (alf(genB) < (unsigned)s) __builtin_amdgcn_s_sleep(2);
            __syncthreads();
            if (active)
                mfma_chunks4(h0buf + rdslot, wv * 256, 0, b0, b1, b2,
                             bfr, L, quad, m_r, acc);
            // ---- L1 phase 2: wait genC >= s (h1 ready), compute h1 half
            if (tid == 0)
                while (alf(genC) < (unsigned)s) __builtin_amdgcn_s_sleep(2);
            __syncthreads();
            if (active)
                mfma_chunks4(h1buf + rdslot, wv * 256, 8, b0, b1, b2,
                             bfr, L, quad, m_r, acc);
        }
        if (active) {
            // zs write: aliases this wave's buf0 -- all buf0 reads retired above
#pragma unroll
            for (int mt = 0; mt < 2; ++mt)
#pragma unroll
                for (int nt = 0; nt < 2; ++nt)
#pragma unroll
                    for (int i = 0; i < 4; ++i)
                        zsw[(mt * 16 + quad * 4 + i) * 32 + nt * 16 + m_r] = acc[mt][nt][i];
        }
        __syncthreads();   // sync1: all waves' zs + zx8 ready

        // ---- Phase C: gate math
        float hval = 0.f, cnv = 0.f;
        if (active) {
            float zi = bi0, zf = bf0, zg = bg0, zo = bo0;
#pragma unroll
            for (int v = 0; v < 4; ++v) {
                const float* zv = (const float*)&ash[v][0][0];
                zi += zv[gb * 32 + gc];      zf += zv[gb * 32 + 8 + gc];
                zg += zv[gb * 32 + 16 + gc]; zo += zv[gb * 32 + 24 + gc];
            }
            if (!lay) {
                zi += b2f(zxloc[gb * 32 + gc]);      zf += b2f(zxloc[gb * 32 + 8 + gc]);
                zg += b2f(zxloc[gb * 32 + 16 + gc]); zo += b2f(zxloc[gb * 32 + 24 + gc]);
            }
            float si = 1.f / (1.f + __expf(-zi));
            float sf = 1.f / (1.f + __expf(-zf));
            float so = 1.f / (1.f + __expf(-zo));
            cnv = sf * creg + si * tanhf(zg);
            creg = cnv;
            hval = so * tanhf(cnv);
            hloc[gb * 8 + gc] = f2bu(hval);
        }
        __syncthreads();   // sync2: hloc ready

        // ---- Phase D: publish h to exchange slot (wave0, LLC-direct)
        if (active && tid < 64) {
            int br = tid >> 1, half = tid & 1;
            unsigned long long v = *(unsigned long long*)(hloc + br * 8 + half * 4);
            unsigned short* dst = (lay ? h1buf : h0buf) + wrslot
                                  + br * 1024 + w * 8 + half * 4;
            ast8(dst, v);
        }
        __syncthreads();   // sync3: drains vmcnt -> h stores at LLC
        unsigned tgt = (unsigned)s + 1u;
        if (tid == 0) astf(flags + wgid, tgt);

        // ---- aggregators
        if (wgid == 0 && tid < 64) {
            unsigned warL1 = (tgt > 2u) ? tgt - 2u : 0u;
            for (;;) {
                unsigned f0 = alf(flags + tid);
                unsigned f1 = alf(flags + 64 + tid);
                unsigned g0 = alf(flags + 128 + tid);
                unsigned g1 = alf(flags + 192 + tid);
                if (__all((f0 >= tgt) && (f1 >= tgt) && (g0 >= warL1) && (g1 >= warL1)))
                    break;
                __builtin_amdgcn_s_sleep(2);
            }
            if (tid < 8)       astf(flags + 320 + tid * 32, tgt);
            else if (tid < 16) astf(flags + 576 + (tid - 8) * 32, tgt);
        }
        if (wgid == 128 && tid < 64) {
            for (;;) {
                unsigned f0 = alf(flags + tid);
                unsigned f1 = alf(flags + 64 + tid);
                unsigned g0 = alf(flags + 128 + tid);
                unsigned g1 = alf(flags + 192 + tid);
                if (__all((f0 >= tgt) && (f1 >= tgt) && (g0 >= tgt) && (g1 >= tgt)))
                    break;
                __builtin_amdgcn_s_sleep(2);
            }
            if (tid < 8) astf(flags + 832 + tid * 32, tgt);
        }
        // out[] stores: off the critical path
        if (active) {
            if (lay) {
                out[((size_t)gb * 512 + t) * 1024 + w * 8 + gc] = hval;
                if (t == 511) {
                    out[16777216 + 32768 + gb * 1024 + w * 8 + gc] = hval;
                    out[16777216 + 65536 + 32768 + gb * 1024 + w * 8 + gc] = cnv;
                }
            } else if (t == 511) {
                out[16777216 + gb * 1024 + w * 8 + gc] = hval;
                out[16777216 + 65536 + gb * 1024 + w * 8 + gc] = cnv;
            }
        }
        // no trailing poll: next iteration's top-of-step gen wait gates reuse.
    }
}

// ---------------------------------------------------------------- launch
extern "C" void kernel_launch(void* const* d_in, const int* in_sizes, int n_in,
                              void* d_out, int out_size, void* d_ws, size_t ws_size,
                              hipStream_t stream) {
    const float* x  = (const float*)d_in[0];
    const float* Wx = (const float*)d_in[1];
    const float* Wh = (const float*)d_in[2];
    const float* bb = (const float*)d_in[3];

    char* ws = (char*)d_ws;
    unsigned short* Wxp  = (unsigned short*)ws;                       //  8MB [4096][1024]
    unsigned short* Whp0 = (unsigned short*)(ws + (8ull  << 20));     //  8MB [4096][1024]
    unsigned short* Wcat = (unsigned short*)(ws + (16ull << 20));     // 16MB [4096][2048]
    unsigned short* xb   = (unsigned short*)(ws + (32ull << 20));     // 32MB
    unsigned short* Zx   = (unsigned short*)(ws + (64ull << 20));     // 128MB
    char* misc           = ws + (192ull << 20);
    float* biasp         = (float*)misc;                              // 16KB
    unsigned* bars       = (unsigned*)(misc + (64 << 10));            // 8KB flags+gens
    unsigned short* h0b  = (unsigned short*)(misc + (128 << 10));     // 256KB [4][32][1024]
    unsigned short* h1b  = (unsigned short*)(misc + (384 << 10));     // 256KB [4][32][1024]
    unsigned* hz         = (unsigned*)(misc + (128 << 10));           // both, 512KB

    float* out = (float*)d_out;

    pack_x<<<16384, 256, 0, stream>>>(x, xb);
    pack_w<<<2048, 256, 0, stream>>>(Wx, Wh, Wxp, Whp0, Wcat);
    pack_misc<<<256, 256, 0, stream>>>(bb, biasp, bars, hz);

    gemm_zx<<<4096, 256, 0, stream>>>(xb, Wxp, biasp, Zx);
    lstm_fused<<<256, 256, 0, stream>>>(Whp0, Wcat, Zx, bb, h0b, h1b, bars, out);
}